// Round 5
// baseline (488.839 us; speedup 1.0000x reference)
//
#include <hip/hip_runtime.h>

typedef __attribute__((ext_vector_type(8))) short short8;
typedef __attribute__((ext_vector_type(4))) float f32x4;
typedef unsigned short u16;
typedef unsigned int u32;

#define CNT_PER_C (8*64*32*32)   // 524288

// workspace offsets (bytes)
#define WS_PART  0          // 1024*2 f32
#define WS_SCALE 8192       // 128 f32
#define WS_SHIFT 8704       // 128 f32
#define WS_WKQV  9216       // 192*128 bf16
#define WS_WO    58368      // 128*64 bf16

__device__ __forceinline__ u16 f2bf(float f){
  u32 u = __builtin_bit_cast(u32, f);
  u32 r = u + 0x7FFFu + ((u >> 16) & 1u);
  return (u16)(r >> 16);
}
__device__ __forceinline__ float bf2f(u16 h){
  u32 u = ((u32)h) << 16;
  return __builtin_bit_cast(float, u);
}

// ---------------- K0: weights -> bf16 ----------------
__global__ void k_prep(const float* wk, const float* wq, const float* wv,
                       const float* wo, u16* wkqv_bf, u16* wo_bf){
  int idx = blockIdx.x*1024 + threadIdx.x*4;
#pragma unroll
  for (int i=0;i<4;i++){
    int id = idx+i;
    if (id < 24576){
      int r = id >> 7, c = id & 127;
      float v = (r<64) ? wk[r*128+c] : (r<128) ? wq[(r-64)*128+c] : wv[(r-128)*128+c];
      wkqv_bf[id] = f2bf(v);
    } else {
      int j = id - 24576;
      wo_bf[j] = f2bf(wo[j]);
    }
  }
}

// ---------------- K1a: per-(c,b) partial sums ----------------
__global__ __launch_bounds__(256) void k_stats1(const float* x, float* part){
  int cb = blockIdx.x; int c = cb>>3, b = cb&7;
  const float4* p = (const float4*)(x + ((size_t)(b*128 + c))*65536);
  int t = threadIdx.x;
  float s=0.f, s2=0.f;
  for (int i=0;i<64;i++){
    float4 v = p[t + i*256];
    s  += v.x+v.y+v.z+v.w;
    s2 += v.x*v.x + v.y*v.y + v.z*v.z + v.w*v.w;
  }
  for (int off=32; off; off>>=1){ s += __shfl_down(s, off, 64); s2 += __shfl_down(s2, off, 64); }
  __shared__ float ls[8];
  int wid = t>>6, lane = t&63;
  if (lane==0){ ls[wid*2]=s; ls[wid*2+1]=s2; }
  __syncthreads();
  if (t==0){
    float S=0.f, S2=0.f;
    for (int wv=0; wv<4; wv++){ S+=ls[wv*2]; S2+=ls[wv*2+1]; }
    part[cb*2]=S; part[cb*2+1]=S2;
  }
}

// ---------------- K1b: finalize scale/shift ----------------
__global__ void k_stats2(const float* part, const float* gamma, const float* beta,
                         float* scale, float* shift){
  int c = threadIdx.x;
  float S=0.f, S2=0.f;
  for (int b=0;b<8;b++){ S += part[(c*8+b)*2]; S2 += part[(c*8+b)*2+1]; }
  float inv = 1.0f/(float)CNT_PER_C;
  float mean = S*inv;
  float var  = S2*inv - mean*mean;
  float rstd = rsqrtf(var + 1e-5f);
  float sc = gamma[c]*rstd;
  scale[c] = sc; shift[c] = beta[c] - mean*sc;
}

// ---------------- K2: fully fused norm + attention + residual ----------------
// One block = (b,h, w-group of 8). 8 waves, wave wid owns sequence w = wg*8+wid.
// LDS: 8 slots x 16KB. Slot layout over time:
//   xn[d][c] bf16 (SWZ16) -> (after frag load) kt|qt 8KB halves (SWZ3)
//   -> vt|a_t -> attn_t|a_t -> o_slab[d][c] (SWZ16).
// SWZ16: u16 idx = d*128 + (c ^ ((d&15)<<3)); SWZ3 (8KB [64][64]): r*64 + (col ^ ((r&7)<<3)).
__global__ __launch_bounds__(512, 2) void k_fused(
    const float* __restrict__ x, const float* __restrict__ scale,
    const float* __restrict__ shift, const u16* __restrict__ wkqv,
    const u16* __restrict__ wo, float* __restrict__ out)
{
  __shared__ u16 sm16[65536];   // 128 KB
  char* smb = (char*)sm16;
  const int t = threadIdx.x;
  const int lane = t & 63, wid = t >> 6;
  const int lr = lane & 15, lk = lane >> 4;

  // bijective XCD-aware mapping: xcd = i&7 gets bh-range [xcd*32, xcd*32+32),
  // consecutive per-XCD blocks cover the 4 w-groups of one bh (L2 line sharing).
  const int i0 = blockIdx.x;
  const int bh = (i0 & 7) * 32 + (i0 >> 5);
  const int wg = (i0 >> 3) & 3;
  const int b = bh >> 5, h = bh & 31;

  // ---------- phase 1: load + normalize -> xn slots ----------
  const int c = t & 127;
  const int dbase = t >> 7;
  const float fsc = scale[c], fsh = shift[c];
  const float* xbase = x + ((size_t)(b*128 + c))*65536 + h*32 + wg*8;

#pragma unroll
  for (int k=0; k<16; k++){
    const int d = dbase + k*4;
    const float* px = xbase + (size_t)d*1024;
    float4 v0 = *(const float4*)px;
    float4 v1 = *(const float4*)(px + 4);
    const int bidx = d*128 + (c ^ ((d&15)<<3));
    sm16[0*8192 + bidx] = f2bf(v0.x*fsc + fsh);
    sm16[1*8192 + bidx] = f2bf(v0.y*fsc + fsh);
    sm16[2*8192 + bidx] = f2bf(v0.z*fsc + fsh);
    sm16[3*8192 + bidx] = f2bf(v0.w*fsc + fsh);
    sm16[4*8192 + bidx] = f2bf(v1.x*fsc + fsh);
    sm16[5*8192 + bidx] = f2bf(v1.y*fsc + fsh);
    sm16[6*8192 + bidx] = f2bf(v1.z*fsc + fsh);
    sm16[7*8192 + bidx] = f2bf(v1.w*fsc + fsh);
  }
  __syncthreads();

  // ---------- phase 2: per-wave attention on its sequence ----------
  {
    char* slot = smb + wid*16384;
    char* lo = slot;            // kt -> vt -> attn_t -> o_slab(lower)
    char* hi = slot + 8192;     // qt -> a_t -> o_slab(upper)

    // xn B-fragments (B[k=c][n=d]); after this the slot is reusable
    short8 xbf[4][4];
#pragma unroll
    for (int ct=0; ct<4; ct++)
#pragma unroll
      for (int ks=0; ks<4; ks++){
        int d = ct*16 + lr;
        xbf[ct][ks] = *(const short8*)(slot + d*256 + (((ks*32 + lk*8)*2) ^ ((d&15)<<4)));
      }

    // ---- GEMM1: K rows 0-63 -> kt[i=d][s'] (lo) ----
#pragma unroll
    for (int mt=0; mt<4; mt++){
      short8 af[4];
#pragma unroll
      for (int ks=0; ks<4; ks++)
        af[ks] = *(const short8*)(wkqv + (size_t)(mt*16 + lr)*128 + ks*32 + lk*8);
      f32x4 acc[4];
#pragma unroll
      for (int ct=0; ct<4; ct++) acc[ct] = (f32x4){0.f,0.f,0.f,0.f};
#pragma unroll
      for (int ct=0; ct<4; ct++)
#pragma unroll
        for (int ks=0; ks<4; ks++)
          acc[ct] = __builtin_amdgcn_mfma_f32_16x16x32_bf16(af[ks], xbf[ct][ks], acc[ct], 0,0,0);
#pragma unroll
      for (int ct=0; ct<4; ct++)
#pragma unroll
        for (int e=0; e<4; e++){
          int d = ct*16 + lr, sp = mt*16 + lk*4 + e;
          *(u16*)(lo + d*128 + ((sp*2) ^ ((d&7)<<4))) = f2bf(acc[ct][e]);
        }
    }
    // ---- GEMM1: Q rows 64-127 -> qt[j=d][s'] (hi) ----
#pragma unroll
    for (int mt=0; mt<4; mt++){
      short8 af[4];
#pragma unroll
      for (int ks=0; ks<4; ks++)
        af[ks] = *(const short8*)(wkqv + (size_t)((mt+4)*16 + lr)*128 + ks*32 + lk*8);
      f32x4 acc[4];
#pragma unroll
      for (int ct=0; ct<4; ct++) acc[ct] = (f32x4){0.f,0.f,0.f,0.f};
#pragma unroll
      for (int ct=0; ct<4; ct++)
#pragma unroll
        for (int ks=0; ks<4; ks++)
          acc[ct] = __builtin_amdgcn_mfma_f32_16x16x32_bf16(af[ks], xbf[ct][ks], acc[ct], 0,0,0);
#pragma unroll
      for (int ct=0; ct<4; ct++)
#pragma unroll
        for (int e=0; e<4; e++){
          int d = ct*16 + lr, sp = mt*16 + lk*4 + e;
          *(u16*)(hi + d*128 + ((sp*2) ^ ((d&7)<<4))) = f2bf(acc[ct][e]);
        }
    }
    // ---- GEMM1: V rows 128-191 -> keep in registers ----
    f32x4 vacc[4][4];
#pragma unroll
    for (int mt=0; mt<4; mt++){
      short8 af[4];
#pragma unroll
      for (int ks=0; ks<4; ks++)
        af[ks] = *(const short8*)(wkqv + (size_t)((mt+8)*16 + lr)*128 + ks*32 + lk*8);
#pragma unroll
      for (int ct=0; ct<4; ct++) vacc[mt][ct] = (f32x4){0.f,0.f,0.f,0.f};
#pragma unroll
      for (int ct=0; ct<4; ct++)
#pragma unroll
        for (int ks=0; ks<4; ks++)
          vacc[mt][ct] = __builtin_amdgcn_mfma_f32_16x16x32_bf16(af[ks], xbf[ct][ks], vacc[mt][ct], 0,0,0);
    }

    // ---- GEMM2 frags: A[i][s']=K^T from kt, then V overwrites kt slot ----
    short8 ka[4][2];
#pragma unroll
    for (int it=0; it<4; it++)
#pragma unroll
      for (int ks=0; ks<2; ks++){
        int i = it*16 + lr;
        ka[it][ks] = *(const short8*)(lo + i*128 + (((ks*32 + lk*8)*2) ^ ((i&7)<<4)));
      }
    // scatter V -> vt[s'][i] into lo (kt frags already read; same-wave DS is in-order)
#pragma unroll
    for (int m4=0; m4<4; m4++)
#pragma unroll
      for (int ct=0; ct<4; ct++)
#pragma unroll
        for (int e=0; e<4; e++){
          int sp = m4*16 + lk*4 + e, i = ct*16 + lr;
          *(u16*)(lo + sp*128 + ((i*2) ^ ((sp&7)<<4))) = f2bf(vacc[m4][ct][e]);
        }
    short8 qb[4][2];
#pragma unroll
    for (int jt=0; jt<4; jt++)
#pragma unroll
      for (int ks=0; ks<2; ks++){
        int j = jt*16 + lr;
        qb[jt][ks] = *(const short8*)(hi + j*128 + (((ks*32 + lk*8)*2) ^ ((j&7)<<4)));
      }
    // scores[i][j] = sum_s' K[s',i] Q[s',j]
    f32x4 sc4[4][4];
#pragma unroll
    for (int it=0; it<4; it++)
#pragma unroll
      for (int jt=0; jt<4; jt++) sc4[it][jt] = (f32x4){0.f,0.f,0.f,0.f};
#pragma unroll
    for (int it=0; it<4; it++)
#pragma unroll
      for (int jt=0; jt<4; jt++)
#pragma unroll
        for (int ks=0; ks<2; ks++)
          sc4[it][jt] = __builtin_amdgcn_mfma_f32_16x16x32_bf16(ka[it][ks], qb[jt][ks], sc4[it][jt], 0,0,0);

    // ---- softmax over i (M-dim) per column j, fully in-register ----
    // column j lives in lanes {lr, lr+16, lr+32, lr+48}; i = it*16 + lk*4 + e
#pragma unroll
    for (int jt=0; jt<4; jt++){
      float m = -1e30f;
#pragma unroll
      for (int it=0; it<4; it++)
#pragma unroll
        for (int e=0; e<4; e++) m = fmaxf(m, sc4[it][jt][e]);
      m = fmaxf(m, __shfl_xor(m, 16, 64));
      m = fmaxf(m, __shfl_xor(m, 32, 64));
      float ssum = 0.f;
#pragma unroll
      for (int it=0; it<4; it++)
#pragma unroll
        for (int e=0; e<4; e++){
          float p = __expf((sc4[it][jt][e] - m) * 0.125f);
          sc4[it][jt][e] = p; ssum += p;
        }
      ssum += __shfl_xor(ssum, 16, 64);
      ssum += __shfl_xor(ssum, 32, 64);
      float inv = 1.0f / ssum;
#pragma unroll
      for (int it=0; it<4; it++)
#pragma unroll
        for (int e=0; e<4; e++){
          int j = jt*16 + lr, i = it*16 + lk*4 + e;
          *(u16*)(hi + j*128 + ((i*2) ^ ((j&7)<<4))) = f2bf(sc4[it][jt][e] * inv);
        }
    }

    // ---- GEMM3: attn[s'][j] = sum_i V[s'][i] a[i][j] ----
    short8 va[4][2], ab[4][2];
#pragma unroll
    for (int st=0; st<4; st++)
#pragma unroll
      for (int ks=0; ks<2; ks++){
        int s2 = st*16 + lr;
        va[st][ks] = *(const short8*)(lo + s2*128 + (((ks*32 + lk*8)*2) ^ ((s2&7)<<4)));
      }
#pragma unroll
    for (int jt=0; jt<4; jt++)
#pragma unroll
      for (int ks=0; ks<2; ks++){
        int j = jt*16 + lr;
        ab[jt][ks] = *(const short8*)(hi + j*128 + (((ks*32 + lk*8)*2) ^ ((j&7)<<4)));
      }
    f32x4 at4[4][4];
#pragma unroll
    for (int st=0; st<4; st++)
#pragma unroll
      for (int jt=0; jt<4; jt++) at4[st][jt] = (f32x4){0.f,0.f,0.f,0.f};
#pragma unroll
    for (int st=0; st<4; st++)
#pragma unroll
      for (int jt=0; jt<4; jt++)
#pragma unroll
        for (int ks=0; ks<2; ks++)
          at4[st][jt] = __builtin_amdgcn_mfma_f32_16x16x32_bf16(va[st][ks], ab[jt][ks], at4[st][jt], 0,0,0);
    // scatter attn_t[d=j][s'] into lo (vt frags already read)
#pragma unroll
    for (int st=0; st<4; st++)
#pragma unroll
      for (int jt=0; jt<4; jt++)
#pragma unroll
        for (int e=0; e<4; e++){
          int sp = st*16 + lk*4 + e, d = jt*16 + lr;
          *(u16*)(lo + d*128 + ((sp*2) ^ ((d&7)<<4))) = f2bf(at4[st][jt][e]);
        }

    // ---- GEMM4: out[c][d] = sum_s' Wo[c][s'] attn[s'][d] -> o_slab[d][c] ----
    short8 tb[4][2];
#pragma unroll
    for (int dt=0; dt<4; dt++)
#pragma unroll
      for (int ks=0; ks<2; ks++){
        int d = dt*16 + lr;
        tb[dt][ks] = *(const short8*)(lo + d*128 + (((ks*32 + lk*8)*2) ^ ((d&7)<<4)));
      }
#pragma unroll
    for (int mt=0; mt<8; mt++){
      short8 wa[2];
#pragma unroll
      for (int ks=0; ks<2; ks++)
        wa[ks] = *(const short8*)(wo + (size_t)(mt*16 + lr)*64 + ks*32 + lk*8);
      f32x4 oa[4];
#pragma unroll
      for (int dt=0; dt<4; dt++) oa[dt] = (f32x4){0.f,0.f,0.f,0.f};
#pragma unroll
      for (int dt=0; dt<4; dt++)
#pragma unroll
        for (int ks=0; ks<2; ks++)
          oa[dt] = __builtin_amdgcn_mfma_f32_16x16x32_bf16(wa[ks], tb[dt][ks], oa[dt], 0,0,0);
#pragma unroll
      for (int dt=0; dt<4; dt++)
#pragma unroll
        for (int e=0; e<4; e++){
          int cc = mt*16 + lk*4 + e, d = dt*16 + lr;
          sm16[wid*8192 + d*128 + (cc ^ ((d&15)<<3))] = f2bf(oa[dt][e]);
        }
    }
  }
  __syncthreads();

  // ---------- phase 3: residual merge, write out ----------
  float* obase = out + ((size_t)(b*128 + c))*65536 + h*32 + wg*8;
#pragma unroll
  for (int k=0; k<16; k++){
    const int d = dbase + k*4;
    const float* px = xbase + (size_t)d*1024;
    float4 v0 = *(const float4*)px;
    float4 v1 = *(const float4*)(px + 4);
    const int bidx = d*128 + (c ^ ((d&15)<<3));
    v0.x += bf2f(sm16[0*8192 + bidx]);
    v0.y += bf2f(sm16[1*8192 + bidx]);
    v0.z += bf2f(sm16[2*8192 + bidx]);
    v0.w += bf2f(sm16[3*8192 + bidx]);
    v1.x += bf2f(sm16[4*8192 + bidx]);
    v1.y += bf2f(sm16[5*8192 + bidx]);
    v1.z += bf2f(sm16[6*8192 + bidx]);
    v1.w += bf2f(sm16[7*8192 + bidx]);
    *(float4*)(obase + (size_t)d*1024) = v0;
    *(float4*)(obase + (size_t)d*1024 + 4) = v1;
  }
}

extern "C" void kernel_launch(void* const* d_in, const int* in_sizes, int n_in,
                              void* d_out, int out_size, void* d_ws, size_t ws_size,
                              hipStream_t stream){
  const float* x     = (const float*)d_in[0];
  const float* Wk    = (const float*)d_in[1];
  const float* Wq    = (const float*)d_in[2];
  const float* Wv    = (const float*)d_in[3];
  const float* Wo    = (const float*)d_in[4];
  const float* gamma = (const float*)d_in[5];
  const float* beta  = (const float*)d_in[6];
  float* out = (float*)d_out;
  char* ws = (char*)d_ws;

  float* part  = (float*)(ws + WS_PART);
  float* scale = (float*)(ws + WS_SCALE);
  float* shift = (float*)(ws + WS_SHIFT);
  u16* wkqv  = (u16*)(ws + WS_WKQV);
  u16* wo_bf = (u16*)(ws + WS_WO);

  k_prep  <<<32,   256, 0, stream>>>(Wk, Wq, Wv, Wo, wkqv, wo_bf);
  k_stats1<<<1024, 256, 0, stream>>>(x, part);
  k_stats2<<<1,    128, 0, stream>>>(part, gamma, beta, scale, shift);
  k_fused <<<1024, 512, 0, stream>>>(x, scale, shift, wkqv, wo_bf, out);
}

// Round 6
// 395.328 us; speedup vs baseline: 1.2365x; 1.2365x over previous
//
#include <hip/hip_runtime.h>

typedef __attribute__((ext_vector_type(8))) short short8;
typedef __attribute__((ext_vector_type(4))) float f32x4;
typedef unsigned short u16;
typedef unsigned int u32;

#define CNT_PER_C (8*64*32*32)   // 524288

// workspace offsets (bytes)
#define WS_PART  0          // 1024*2 f32
#define WS_SCALE 8192       // 128 f32
#define WS_SHIFT 8704       // 128 f32
#define WS_WKQV  9216       // 192*128 bf16
#define WS_WO    58368      // 128*64 bf16
#define WS_OUTP  131072     // 8192 * 8192 bf16 = 134217728

__device__ __forceinline__ u16 f2bf(float f){
  u32 u = __builtin_bit_cast(u32, f);
  u32 r = u + 0x7FFFu + ((u >> 16) & 1u);
  return (u16)(r >> 16);
}
__device__ __forceinline__ float bf2f(u16 h){
  u32 u = ((u32)h) << 16;
  return __builtin_bit_cast(float, u);
}

#define SWZ(colbyte, row) ((colbyte) ^ (((row)&7)<<4))

// ---------------- K0: weights -> bf16 ----------------
__global__ void k_prep(const float* wk, const float* wq, const float* wv,
                       const float* wo, u16* wkqv_bf, u16* wo_bf){
  int idx = blockIdx.x*1024 + threadIdx.x*4;
#pragma unroll
  for (int i=0;i<4;i++){
    int id = idx+i;
    if (id < 24576){
      int r = id >> 7, c = id & 127;
      float v = (r<64) ? wk[r*128+c] : (r<128) ? wq[(r-64)*128+c] : wv[(r-128)*128+c];
      wkqv_bf[id] = f2bf(v);
    } else {
      int j = id - 24576;
      wo_bf[j] = f2bf(wo[j]);
    }
  }
}

// ---------------- K1a: per-(c,b) partial sums ----------------
__global__ __launch_bounds__(256) void k_stats1(const float* x, float* part){
  int cb = blockIdx.x; int c = cb>>3, b = cb&7;
  const float4* p = (const float4*)(x + ((size_t)(b*128 + c))*65536);
  int t = threadIdx.x;
  float s=0.f, s2=0.f;
  for (int i=0;i<64;i++){
    float4 v = p[t + i*256];
    s  += v.x+v.y+v.z+v.w;
    s2 += v.x*v.x + v.y*v.y + v.z*v.z + v.w*v.w;
  }
  for (int off=32; off; off>>=1){ s += __shfl_down(s, off, 64); s2 += __shfl_down(s2, off, 64); }
  __shared__ float ls[8];
  int wid = t>>6, lane = t&63;
  if (lane==0){ ls[wid*2]=s; ls[wid*2+1]=s2; }
  __syncthreads();
  if (t==0){
    float S=0.f, S2=0.f;
    for (int wv=0; wv<4; wv++){ S+=ls[wv*2]; S2+=ls[wv*2+1]; }
    part[cb*2]=S; part[cb*2+1]=S2;
  }
}

// ---------------- K1b: finalize scale/shift ----------------
__global__ void k_stats2(const float* part, const float* gamma, const float* beta,
                         float* scale, float* shift){
  int c = threadIdx.x;
  float S=0.f, S2=0.f;
  for (int b=0;b<8;b++){ S += part[(c*8+b)*2]; S2 += part[(c*8+b)*2+1]; }
  float inv = 1.0f/(float)CNT_PER_C;
  float mean = S*inv;
  float var  = S2*inv - mean*mean;
  float rstd = rsqrtf(var + 1e-5f);
  float sc = gamma[c]*rstd;
  scale[c] = sc; shift[c] = beta[c] - mean*sc;
}

// ---------------- K2: normalize + transpose -> xn_t[n][d][c] bf16 ----------------
__global__ __launch_bounds__(256) void k_norm_t(const float* x, const float* scale,
                                                const float* shift, u16* xn_t){
  __shared__ u16 lm[32*512];           // 32 KB
  __shared__ float lsc[128], lsh[128];
  int t = threadIdx.x;
  if (t < 128){ lsc[t] = scale[t]; lsh[t] = shift[t]; }
  int bid = blockIdx.x;
  int bh = bid>>3, dq = bid&7;
  int b = bh>>5, h = bh&31;
  int d0 = dq*8, n0 = bh*32;
  int s = t>>3, q = t&7;
  __syncthreads();
  for (int h2=0; h2<2; h2++){
    int w4 = q*4;
#pragma unroll
    for (int i=0;i<16;i++){
      int rowpos = i*32 + s;
      int cl = rowpos & 63, dd = rowpos >> 6;
      int c = h2*64 + cl;
      float4 v = *(const float4*)(x + ((size_t)((b*128 + c)*64 + d0 + dd))*1024 + h*32 + w4);
      float sc = lsc[c], sh = lsh[c];
      lm[(w4+0)*512 + (rowpos ^ ((w4+0)&28))] = f2bf(v.x*sc + sh);
      lm[(w4+1)*512 + (rowpos ^ ((w4+1)&28))] = f2bf(v.y*sc + sh);
      lm[(w4+2)*512 + (rowpos ^ ((w4+2)&28))] = f2bf(v.z*sc + sh);
      lm[(w4+3)*512 + (rowpos ^ ((w4+3)&28))] = f2bf(v.w*sc + sh);
    }
    __syncthreads();
    {
      int n = s, oct = q;
      int oq = oct ^ ((n>>3)&3);
      bool swp = (n & 4) != 0;
#pragma unroll
      for (int m=0;m<8;m++){
        uint4 raw = *(const uint4*)&lm[n*512 + m*64 + oq*8];
        if (swp){ u32 tx=raw.x, ty=raw.y; raw.x=raw.z; raw.y=raw.w; raw.z=tx; raw.w=ty; }
        *(uint4*)(xn_t + (size_t)(n0+n)*8192 + (size_t)(d0+m)*128 + h2*64 + oct*8) = raw;
      }
    }
    __syncthreads();
  }
}

// ---------------- K3: per-wave fused attention (no barriers) ----------------
// 4 waves/block, wave wid owns sequence n = bid*4+wid and LDS slot (16 KB).
// Slot timeline: xn[d][c] (SWZ16) -> kt(lo)/qt(hi) [row][64 vals] SWZ3
//   -> vt(lo)/a_t(hi) -> attn_t(lo) -> o_slab[c][d] SWZ3 (full slot) -> store.
__global__ __launch_bounds__(256, 2) void k_attn(const u16* __restrict__ xn_t,
                                                 const u16* __restrict__ wkqv,
                                                 const u16* __restrict__ wo,
                                                 u16* __restrict__ out_pre){
  __shared__ alignas(16) char smb[65536];   // 4 x 16 KB
  const int t = threadIdx.x, lane = t & 63, wid = t >> 6;
  const int lr = lane & 15, lk = lane >> 4;
  const int n = blockIdx.x*4 + wid;
  char* slot = smb + wid*16384;
  char* lo = slot;
  char* hi = slot + 8192;
  const u16* xg = xn_t + (size_t)n*8192;

  // ---- stage xn[d][c] into slot, SWZ16 (byte ^ ((d&15)<<4)) ----
#pragma unroll
  for (int r=0;r<16;r++){
    int blk = r*64 + lane;
    int d = blk>>4, cbk = blk&15;
    uint4 v = *(const uint4*)(xg + blk*8);
    *(uint4*)(slot + d*256 + ((cbk*16) ^ ((d&15)<<4))) = v;
  }

  // ---- xn B-fragments (B[k=c][n=d]) ----
  short8 xbf[4][4];
#pragma unroll
  for (int ct=0; ct<4; ct++)
#pragma unroll
    for (int ks=0; ks<4; ks++){
      int d = ct*16 + lr;
      xbf[ct][ks] = *(const short8*)(slot + d*256 + (((ks*32 + lk*8)*2) ^ ((d&15)<<4)));
    }

  // ---- GEMM1: K rows 0-63 -> kt[i=d][s'] (lo, SWZ3) ----
#pragma unroll
  for (int mt=0; mt<4; mt++){
    short8 af[4];
#pragma unroll
    for (int ks=0; ks<4; ks++)
      af[ks] = *(const short8*)(wkqv + (size_t)(mt*16 + lr)*128 + ks*32 + lk*8);
    f32x4 acc[4];
#pragma unroll
    for (int ct=0; ct<4; ct++) acc[ct] = (f32x4){0.f,0.f,0.f,0.f};
#pragma unroll
    for (int ct=0; ct<4; ct++)
#pragma unroll
      for (int ks=0; ks<4; ks++)
        acc[ct] = __builtin_amdgcn_mfma_f32_16x16x32_bf16(af[ks], xbf[ct][ks], acc[ct], 0,0,0);
#pragma unroll
    for (int ct=0; ct<4; ct++)
#pragma unroll
      for (int e=0; e<4; e++){
        int d = ct*16 + lr, sp = mt*16 + lk*4 + e;
        *(u16*)(lo + d*128 + ((sp*2) ^ ((d&7)<<4))) = f2bf(acc[ct][e]);
      }
  }
  // ---- GEMM1: Q rows 64-127 -> qt[j=d][s'] (hi, SWZ3) ----
#pragma unroll
  for (int mt=0; mt<4; mt++){
    short8 af[4];
#pragma unroll
    for (int ks=0; ks<4; ks++)
      af[ks] = *(const short8*)(wkqv + (size_t)((mt+4)*16 + lr)*128 + ks*32 + lk*8);
    f32x4 acc[4];
#pragma unroll
    for (int ct=0; ct<4; ct++) acc[ct] = (f32x4){0.f,0.f,0.f,0.f};
#pragma unroll
    for (int ct=0; ct<4; ct++)
#pragma unroll
      for (int ks=0; ks<4; ks++)
        acc[ct] = __builtin_amdgcn_mfma_f32_16x16x32_bf16(af[ks], xbf[ct][ks], acc[ct], 0,0,0);
#pragma unroll
    for (int ct=0; ct<4; ct++)
#pragma unroll
      for (int e=0; e<4; e++){
        int d = ct*16 + lr, sp = mt*16 + lk*4 + e;
        *(u16*)(hi + d*128 + ((sp*2) ^ ((d&7)<<4))) = f2bf(acc[ct][e]);
      }
  }
  // ---- GEMM1: V rows 128-191 -> registers ----
  f32x4 vacc[4][4];
#pragma unroll
  for (int mt=0; mt<4; mt++){
    short8 af[4];
#pragma unroll
    for (int ks=0; ks<4; ks++)
      af[ks] = *(const short8*)(wkqv + (size_t)((mt+8)*16 + lr)*128 + ks*32 + lk*8);
#pragma unroll
    for (int ct=0; ct<4; ct++) vacc[mt][ct] = (f32x4){0.f,0.f,0.f,0.f};
#pragma unroll
    for (int ct=0; ct<4; ct++)
#pragma unroll
      for (int ks=0; ks<4; ks++)
        vacc[mt][ct] = __builtin_amdgcn_mfma_f32_16x16x32_bf16(af[ks], xbf[ct][ks], vacc[mt][ct], 0,0,0);
  }

  // ---- GEMM2 frags: A[i][s'] = K^T from kt; then V overwrites lo ----
  short8 ka[4][2];
#pragma unroll
  for (int it=0; it<4; it++)
#pragma unroll
    for (int ks=0; ks<2; ks++){
      int i = it*16 + lr;
      ka[it][ks] = *(const short8*)(lo + i*128 + (((ks*32 + lk*8)*2) ^ ((i&7)<<4)));
    }
  // scatter V -> vt[s'][i] into lo (kt frags already in regs; same-wave DS is in-order)
#pragma unroll
  for (int m4=0; m4<4; m4++)
#pragma unroll
    for (int ct=0; ct<4; ct++)
#pragma unroll
      for (int e=0; e<4; e++){
        int sp = m4*16 + lk*4 + e, i = ct*16 + lr;
        *(u16*)(lo + sp*128 + ((i*2) ^ ((sp&7)<<4))) = f2bf(vacc[m4][ct][e]);
      }
  short8 qb[4][2];
#pragma unroll
  for (int jt=0; jt<4; jt++)
#pragma unroll
    for (int ks=0; ks<2; ks++){
      int j = jt*16 + lr;
      qb[jt][ks] = *(const short8*)(hi + j*128 + (((ks*32 + lk*8)*2) ^ ((j&7)<<4)));
    }
  // scores[i][j] = sum_s' K[s',i] Q[s',j]
  f32x4 sc4[4][4];
#pragma unroll
  for (int it=0; it<4; it++)
#pragma unroll
    for (int jt=0; jt<4; jt++) sc4[it][jt] = (f32x4){0.f,0.f,0.f,0.f};
#pragma unroll
  for (int it=0; it<4; it++)
#pragma unroll
    for (int jt=0; jt<4; jt++)
#pragma unroll
      for (int ks=0; ks<2; ks++)
        sc4[it][jt] = __builtin_amdgcn_mfma_f32_16x16x32_bf16(ka[it][ks], qb[jt][ks], sc4[it][jt], 0,0,0);

  // ---- softmax over i per column j, in-register ----
#pragma unroll
  for (int jt=0; jt<4; jt++){
    float m = -1e30f;
#pragma unroll
    for (int it=0; it<4; it++)
#pragma unroll
      for (int e=0; e<4; e++) m = fmaxf(m, sc4[it][jt][e]);
    m = fmaxf(m, __shfl_xor(m, 16, 64));
    m = fmaxf(m, __shfl_xor(m, 32, 64));
    float ssum = 0.f;
#pragma unroll
    for (int it=0; it<4; it++)
#pragma unroll
      for (int e=0; e<4; e++){
        float p = __expf((sc4[it][jt][e] - m) * 0.125f);
        sc4[it][jt][e] = p; ssum += p;
      }
    ssum += __shfl_xor(ssum, 16, 64);
    ssum += __shfl_xor(ssum, 32, 64);
    float inv = 1.0f / ssum;
#pragma unroll
    for (int it=0; it<4; it++)
#pragma unroll
      for (int e=0; e<4; e++){
        int j = jt*16 + lr, i = it*16 + lk*4 + e;
        *(u16*)(hi + j*128 + ((i*2) ^ ((j&7)<<4))) = f2bf(sc4[it][jt][e] * inv);
      }
  }

  // ---- GEMM3: attn[s'][j] = sum_i V[s'][i] a[i][j] -> attn_t[d=j][s'] (lo) ----
  short8 va[4][2], ab[4][2];
#pragma unroll
  for (int st=0; st<4; st++)
#pragma unroll
    for (int ks=0; ks<2; ks++){
      int s2 = st*16 + lr;
      va[st][ks] = *(const short8*)(lo + s2*128 + (((ks*32 + lk*8)*2) ^ ((s2&7)<<4)));
    }
#pragma unroll
  for (int jt=0; jt<4; jt++)
#pragma unroll
    for (int ks=0; ks<2; ks++){
      int j = jt*16 + lr;
      ab[jt][ks] = *(const short8*)(hi + j*128 + (((ks*32 + lk*8)*2) ^ ((j&7)<<4)));
    }
  f32x4 at4[4][4];
#pragma unroll
  for (int st=0; st<4; st++)
#pragma unroll
    for (int jt=0; jt<4; jt++) at4[st][jt] = (f32x4){0.f,0.f,0.f,0.f};
#pragma unroll
  for (int st=0; st<4; st++)
#pragma unroll
    for (int jt=0; jt<4; jt++)
#pragma unroll
      for (int ks=0; ks<2; ks++)
        at4[st][jt] = __builtin_amdgcn_mfma_f32_16x16x32_bf16(va[st][ks], ab[jt][ks], at4[st][jt], 0,0,0);
#pragma unroll
  for (int st=0; st<4; st++)
#pragma unroll
    for (int jt=0; jt<4; jt++)
#pragma unroll
      for (int e=0; e<4; e++){
        int sp = st*16 + lk*4 + e, d = jt*16 + lr;
        *(u16*)(lo + d*128 + ((sp*2) ^ ((d&7)<<4))) = f2bf(at4[st][jt][e]);
      }

  // ---- GEMM4: out[c][d] = sum_s' Wo[c][s'] attn[s'][d] -> o_slab[c][d] (full slot) ----
  short8 tb[4][2];
#pragma unroll
  for (int dt=0; dt<4; dt++)
#pragma unroll
    for (int ks=0; ks<2; ks++){
      int d = dt*16 + lr;
      tb[dt][ks] = *(const short8*)(lo + d*128 + (((ks*32 + lk*8)*2) ^ ((d&7)<<4)));
    }
#pragma unroll
  for (int mt=0; mt<8; mt++){
    short8 wa[2];
#pragma unroll
    for (int ks=0; ks<2; ks++)
      wa[ks] = *(const short8*)(wo + (size_t)(mt*16 + lr)*64 + ks*32 + lk*8);
    f32x4 oa[4];
#pragma unroll
    for (int dt=0; dt<4; dt++) oa[dt] = (f32x4){0.f,0.f,0.f,0.f};
#pragma unroll
    for (int dt=0; dt<4; dt++)
#pragma unroll
      for (int ks=0; ks<2; ks++)
        oa[dt] = __builtin_amdgcn_mfma_f32_16x16x32_bf16(wa[ks], tb[dt][ks], oa[dt], 0,0,0);
#pragma unroll
    for (int dt=0; dt<4; dt++)
#pragma unroll
      for (int e=0; e<4; e++){
        int cc = mt*16 + lk*4 + e, d = dt*16 + lr;
        *(u16*)(slot + cc*128 + ((d*2) ^ ((cc&7)<<4))) = f2bf(oa[dt][e]);
      }
  }

  // ---- coalesced store: out_pre[n][c][d] ----
  u16* og = out_pre + (size_t)n*8192;
#pragma unroll
  for (int r=0;r<16;r++){
    int j = r*64 + lane;          // j = cc*8 + o (o = d-octet)
    int cc = j>>3, o = j&7;
    uint4 v = *(const uint4*)(slot + cc*128 + ((o ^ (cc&7))*16));
    *(uint4*)(og + j*8) = v;
  }
}

// ---------------- K4: out = x + untranspose(out_pre) ----------------
__global__ __launch_bounds__(256) void k_merge(const float* x, const u16* out_pre, float* out){
  __shared__ u16 lm[32*512];   // 32 KB
  int t = threadIdx.x;
  int bid = blockIdx.x;
  int bh = bid>>2, cq = bid&3;
  int b = bh>>5, h = bh&31;
  int n0 = bh*32;
  int cbase = cq*32;
  int s = t>>3, q = t&7;
  for (int cc=0; cc<4; cc++){
    int cb = cbase + cc*8;
    {
      int n = s;
      int oq = q ^ ((n>>3)&3);
      bool swp = (n & 4) != 0;
#pragma unroll
      for (int i=0;i<8;i++){
        uint4 raw = *(const uint4*)(out_pre + (size_t)(n0+n)*8192 + (cb+i)*64 + q*8);
        if (swp){ u32 tx=raw.x, ty=raw.y; raw.x=raw.z; raw.y=raw.w; raw.z=tx; raw.w=ty; }
        *(uint4*)&lm[n*512 + i*64 + oq*8] = raw;
      }
    }
    __syncthreads();
    {
      int w4 = q*4;
#pragma unroll
      for (int g=0; g<16; g++){
        int row = g*32 + s;
        int ci = row>>6, d = row&63;
        size_t gi = ((size_t)((b*128 + cb + ci)*64 + d))*1024 + h*32 + w4;
        float4 xv = *(const float4*)(x + gi);
        float4 ov;
        ov.x = xv.x + bf2f(lm[(w4+0)*512 + (row ^ ((w4+0)&28))]);
        ov.y = xv.y + bf2f(lm[(w4+1)*512 + (row ^ ((w4+1)&28))]);
        ov.z = xv.z + bf2f(lm[(w4+2)*512 + (row ^ ((w4+2)&28))]);
        ov.w = xv.w + bf2f(lm[(w4+3)*512 + (row ^ ((w4+3)&28))]);
        *(float4*)(out + gi) = ov;
      }
    }
    __syncthreads();
  }
}

extern "C" void kernel_launch(void* const* d_in, const int* in_sizes, int n_in,
                              void* d_out, int out_size, void* d_ws, size_t ws_size,
                              hipStream_t stream){
  const float* x     = (const float*)d_in[0];
  const float* Wk    = (const float*)d_in[1];
  const float* Wq    = (const float*)d_in[2];
  const float* Wv    = (const float*)d_in[3];
  const float* Wo    = (const float*)d_in[4];
  const float* gamma = (const float*)d_in[5];
  const float* beta  = (const float*)d_in[6];
  float* out = (float*)d_out;
  char* ws = (char*)d_ws;

  float* part  = (float*)(ws + WS_PART);
  float* scale = (float*)(ws + WS_SCALE);
  float* shift = (float*)(ws + WS_SHIFT);
  u16* wkqv  = (u16*)(ws + WS_WKQV);
  u16* wo_bf = (u16*)(ws + WS_WO);
  u16* outp  = (u16*)(ws + WS_OUTP);
  u16* xn_t  = (u16*)d_out;   // scratch in d_out; dead before k_merge writes

  k_prep  <<<32,   256, 0, stream>>>(Wk, Wq, Wv, Wo, wkqv, wo_bf);
  k_stats1<<<1024, 256, 0, stream>>>(x, part);
  k_stats2<<<1,    128, 0, stream>>>(part, gamma, beta, scale, shift);
  k_norm_t<<<2048, 256, 0, stream>>>(x, scale, shift, xn_t);
  k_attn  <<<2048, 256, 0, stream>>>(xn_t, wkqv, wo_bf, outp);
  k_merge <<<1024, 256, 0, stream>>>(x, outp, out);
}

// Round 8
// 387.712 us; speedup vs baseline: 1.2608x; 1.0196x over previous
//
#include <hip/hip_runtime.h>

typedef __attribute__((ext_vector_type(8))) short short8;
typedef __attribute__((ext_vector_type(4))) float f32x4;
typedef unsigned short u16;
typedef unsigned int u32;

#define CNT_PER_C (8*64*32*32)   // 524288

// workspace offsets (bytes)
#define WS_PART  0          // 1024*2 f32
#define WS_SCALE 8192       // 128 f32
#define WS_SHIFT 8704       // 128 f32
#define WS_WKQV  9216       // 192*128 bf16
#define WS_WO    58368      // 128*64 bf16
#define WS_OUTP  131072     // 8192 * 8192 bf16 = 134217728

__device__ __forceinline__ u16 f2bf(float f){
  u32 u = __builtin_bit_cast(u32, f);
  u32 r = u + 0x7FFFu + ((u >> 16) & 1u);
  return (u16)(r >> 16);
}
__device__ __forceinline__ float bf2f(u16 h){
  u32 u = ((u32)h) << 16;
  return __builtin_bit_cast(float, u);
}
// pack two f32 -> two bf16 in one u32 (lo = a, hi = b); pure C, bit-identical to f2bf pairs
__device__ __forceinline__ u32 pk2(float a, float b){
  return (u32)f2bf(a) | ((u32)f2bf(b) << 16);
}

// ---------------- K0: weights -> bf16 ----------------
__global__ void k_prep(const float* wk, const float* wq, const float* wv,
                       const float* wo, u16* wkqv_bf, u16* wo_bf){
  int idx = blockIdx.x*1024 + threadIdx.x*4;
#pragma unroll
  for (int i=0;i<4;i++){
    int id = idx+i;
    if (id < 24576){
      int r = id >> 7, c = id & 127;
      float v = (r<64) ? wk[r*128+c] : (r<128) ? wq[(r-64)*128+c] : wv[(r-128)*128+c];
      wkqv_bf[id] = f2bf(v);
    } else {
      int j = id - 24576;
      wo_bf[j] = f2bf(wo[j]);
    }
  }
}

// ---------------- K1a: per-(c,b) partial sums ----------------
__global__ __launch_bounds__(256) void k_stats1(const float* x, float* part){
  int cb = blockIdx.x; int c = cb>>3, b = cb&7;
  const float4* p = (const float4*)(x + ((size_t)(b*128 + c))*65536);
  int t = threadIdx.x;
  float s=0.f, s2=0.f;
  for (int i=0;i<64;i++){
    float4 v = p[t + i*256];
    s  += v.x+v.y+v.z+v.w;
    s2 += v.x*v.x + v.y*v.y + v.z*v.z + v.w*v.w;
  }
  for (int off=32; off; off>>=1){ s += __shfl_down(s, off, 64); s2 += __shfl_down(s2, off, 64); }
  __shared__ float ls[8];
  int wid = t>>6, lane = t&63;
  if (lane==0){ ls[wid*2]=s; ls[wid*2+1]=s2; }
  __syncthreads();
  if (t==0){
    float S=0.f, S2=0.f;
    for (int wv=0; wv<4; wv++){ S+=ls[wv*2]; S2+=ls[wv*2+1]; }
    part[cb*2]=S; part[cb*2+1]=S2;
  }
}

// ---------------- K1b: finalize scale/shift ----------------
__global__ void k_stats2(const float* part, const float* gamma, const float* beta,
                         float* scale, float* shift){
  int c = threadIdx.x;
  float S=0.f, S2=0.f;
  for (int b=0;b<8;b++){ S += part[(c*8+b)*2]; S2 += part[(c*8+b)*2+1]; }
  float inv = 1.0f/(float)CNT_PER_C;
  float mean = S*inv;
  float var  = S2*inv - mean*mean;
  float rstd = rsqrtf(var + 1e-5f);
  float sc = gamma[c]*rstd;
  scale[c] = sc; shift[c] = beta[c] - mean*sc;
}

// ---------------- K2: normalize + transpose -> xn_t[n][d][c] bf16 ----------------
__global__ __launch_bounds__(256) void k_norm_t(const float* x, const float* scale,
                                                const float* shift, u16* xn_t){
  __shared__ u16 lm[32*512];           // 32 KB
  __shared__ float lsc[128], lsh[128];
  int t = threadIdx.x;
  if (t < 128){ lsc[t] = scale[t]; lsh[t] = shift[t]; }
  int bid = blockIdx.x;
  int bh = bid>>3, dq = bid&7;
  int b = bh>>5, h = bh&31;
  int d0 = dq*8, n0 = bh*32;
  int s = t>>3, q = t&7;
  __syncthreads();
  for (int h2=0; h2<2; h2++){
    int w4 = q*4;
#pragma unroll
    for (int i=0;i<16;i++){
      int rowpos = i*32 + s;
      int cl = rowpos & 63, dd = rowpos >> 6;
      int c = h2*64 + cl;
      float4 v = *(const float4*)(x + ((size_t)((b*128 + c)*64 + d0 + dd))*1024 + h*32 + w4);
      float sc = lsc[c], sh = lsh[c];
      lm[(w4+0)*512 + (rowpos ^ ((w4+0)&28))] = f2bf(v.x*sc + sh);
      lm[(w4+1)*512 + (rowpos ^ ((w4+1)&28))] = f2bf(v.y*sc + sh);
      lm[(w4+2)*512 + (rowpos ^ ((w4+2)&28))] = f2bf(v.z*sc + sh);
      lm[(w4+3)*512 + (rowpos ^ ((w4+3)&28))] = f2bf(v.w*sc + sh);
    }
    __syncthreads();
    {
      int n = s, oct = q;
      int oq = oct ^ ((n>>3)&3);
      bool swp = (n & 4) != 0;
#pragma unroll
      for (int m=0;m<8;m++){
        uint4 raw = *(const uint4*)&lm[n*512 + m*64 + oq*8];
        if (swp){ u32 tx=raw.x, ty=raw.y; raw.x=raw.z; raw.y=raw.w; raw.z=tx; raw.w=ty; }
        *(uint4*)(xn_t + (size_t)(n0+n)*8192 + (size_t)(d0+m)*128 + h2*64 + oct*8) = raw;
      }
    }
    __syncthreads();
  }
}

// ---------------- K3: per-wave fused attention (no barriers) ----------------
// R6-proven structure. Changes vs R6 (both value-identical to R6):
//  (1) xn fragments loaded directly from global (staging removed);
//  (2) kt/qt/a_t/attn_t scatters packed as uint2 (pure-C pk2), same bytes as R6.
// V-GEMM and Wo-GEMM keep R6's exact math and scalar scatters.
__global__ __launch_bounds__(256, 2) void k_attn(const u16* __restrict__ xn_t,
                                                 const u16* __restrict__ wkqv,
                                                 const u16* __restrict__ wo,
                                                 u16* __restrict__ out_pre){
  __shared__ alignas(16) char smb[65536];   // 4 x 16 KB
  const int t = threadIdx.x, lane = t & 63, wid = t >> 6;
  const int lr = lane & 15, lk = lane >> 4;
  const int n = blockIdx.x*4 + wid;
  char* slot = smb + wid*16384;
  char* lo = slot;
  char* hi = slot + 8192;
  const u16* xg = xn_t + (size_t)n*8192;

  // ---- xn B-fragments direct from global: value = xn_t[n][d=ct*16+lr][c=ks*32+lk*8..+7] ----
  short8 xbf[4][4];
#pragma unroll
  for (int ct=0; ct<4; ct++)
#pragma unroll
    for (int ks=0; ks<4; ks++)
      xbf[ct][ks] = *(const short8*)(xg + (ct*16+lr)*128 + ks*32 + lk*8);

  // ---- GEMM1-K: C[s][d] -> kt[d][s] (lo), packed b64 ----
#pragma unroll
  for (int mt=0; mt<4; mt++){
    short8 af[4];
#pragma unroll
    for (int ks=0; ks<4; ks++)
      af[ks] = *(const short8*)(wkqv + (size_t)(mt*16 + lr)*128 + ks*32 + lk*8);
#pragma unroll
    for (int ct=0; ct<4; ct++){
      f32x4 a = (f32x4){0.f,0.f,0.f,0.f};
#pragma unroll
      for (int ks=0; ks<4; ks++)
        a = __builtin_amdgcn_mfma_f32_16x16x32_bf16(af[ks], xbf[ct][ks], a, 0,0,0);
      int d = ct*16 + lr;
      *(uint2*)(lo + d*128 + ((mt*32 + lk*8) ^ ((d&7)<<4))) =
        (uint2){pk2(a[0],a[1]), pk2(a[2],a[3])};
    }
  }
  // ---- GEMM1-Q: C[s][j] -> qt[j][s] (hi), packed b64 ----
#pragma unroll
  for (int mt=0; mt<4; mt++){
    short8 af[4];
#pragma unroll
    for (int ks=0; ks<4; ks++)
      af[ks] = *(const short8*)(wkqv + (size_t)((mt+4)*16 + lr)*128 + ks*32 + lk*8);
#pragma unroll
    for (int ct=0; ct<4; ct++){
      f32x4 a = (f32x4){0.f,0.f,0.f,0.f};
#pragma unroll
      for (int ks=0; ks<4; ks++)
        a = __builtin_amdgcn_mfma_f32_16x16x32_bf16(af[ks], xbf[ct][ks], a, 0,0,0);
      int d = ct*16 + lr;
      *(uint2*)(hi + d*128 + ((mt*32 + lk*8) ^ ((d&7)<<4))) =
        (uint2){pk2(a[0],a[1]), pk2(a[2],a[3])};
    }
  }
  // ---- GEMM1-V: rows 128-191 -> registers (R6 verbatim) ----
  f32x4 vacc[4][4];
#pragma unroll
  for (int mt=0; mt<4; mt++){
    short8 af[4];
#pragma unroll
    for (int ks=0; ks<4; ks++)
      af[ks] = *(const short8*)(wkqv + (size_t)((mt+8)*16 + lr)*128 + ks*32 + lk*8);
#pragma unroll
    for (int ct=0; ct<4; ct++) vacc[mt][ct] = (f32x4){0.f,0.f,0.f,0.f};
#pragma unroll
    for (int ct=0; ct<4; ct++)
#pragma unroll
      for (int ks=0; ks<4; ks++)
        vacc[mt][ct] = __builtin_amdgcn_mfma_f32_16x16x32_bf16(af[ks], xbf[ct][ks], vacc[mt][ct], 0,0,0);
  }

  // ---- ka frags from kt (before V overwrites lo) ----
  short8 ka[4][2];
#pragma unroll
  for (int it=0; it<4; it++)
#pragma unroll
    for (int ks2=0; ks2<2; ks2++){
      int i = it*16 + lr;
      ka[it][ks2] = *(const short8*)(lo + i*128 + ((ks2*64 + lk*16) ^ ((i&7)<<4)));
    }
  // ---- scatter V -> vt[s'][i] (lo), scalar (R6 verbatim) ----
#pragma unroll
  for (int m4=0; m4<4; m4++)
#pragma unroll
    for (int ct=0; ct<4; ct++)
#pragma unroll
      for (int e=0; e<4; e++){
        int sp = m4*16 + lk*4 + e, i = ct*16 + lr;
        *(u16*)(lo + sp*128 + ((i*2) ^ ((sp&7)<<4))) = f2bf(vacc[m4][ct][e]);
      }
  short8 qb[4][2];
#pragma unroll
  for (int jt=0; jt<4; jt++)
#pragma unroll
    for (int ks2=0; ks2<2; ks2++){
      int j = jt*16 + lr;
      qb[jt][ks2] = *(const short8*)(hi + j*128 + ((ks2*64 + lk*16) ^ ((j&7)<<4)));
    }
  // ---- GEMM2: scores[i][j] = sum_s' K[s',i] Q[s',j] ----
  f32x4 sc4[4][4];
#pragma unroll
  for (int it=0; it<4; it++)
#pragma unroll
    for (int jt=0; jt<4; jt++) sc4[it][jt] = (f32x4){0.f,0.f,0.f,0.f};
#pragma unroll
  for (int it=0; it<4; it++)
#pragma unroll
    for (int jt=0; jt<4; jt++)
#pragma unroll
      for (int ks2=0; ks2<2; ks2++)
        sc4[it][jt] = __builtin_amdgcn_mfma_f32_16x16x32_bf16(ka[it][ks2], qb[jt][ks2], sc4[it][jt], 0,0,0);

  // ---- softmax over i per column j -> a_t[j][i] (hi), packed b64 ----
#pragma unroll
  for (int jt=0; jt<4; jt++){
    float m = -1e30f;
#pragma unroll
    for (int it=0; it<4; it++)
#pragma unroll
      for (int e=0; e<4; e++) m = fmaxf(m, sc4[it][jt][e]);
    m = fmaxf(m, __shfl_xor(m, 16, 64));
    m = fmaxf(m, __shfl_xor(m, 32, 64));
    float ssum = 0.f;
#pragma unroll
    for (int it=0; it<4; it++)
#pragma unroll
      for (int e=0; e<4; e++){
        float p = __expf((sc4[it][jt][e] - m) * 0.125f);
        sc4[it][jt][e] = p; ssum += p;
      }
    ssum += __shfl_xor(ssum, 16, 64);
    ssum += __shfl_xor(ssum, 32, 64);
    float inv = 1.0f / ssum;
    int j = jt*16 + lr;
#pragma unroll
    for (int it=0; it<4; it++){
      *(uint2*)(hi + j*128 + ((it*32 + lk*8) ^ ((j&7)<<4))) =
        (uint2){pk2(sc4[it][jt][0]*inv, sc4[it][jt][1]*inv),
                pk2(sc4[it][jt][2]*inv, sc4[it][jt][3]*inv)};
    }
  }

  // ---- GEMM3: attn[s'][j] = sum_i V[s'][i] a[i][j] -> attn_t[d=j][s'] (lo), packed b64 ----
  short8 va[4][2], ab[4][2];
#pragma unroll
  for (int st=0; st<4; st++)
#pragma unroll
    for (int ks2=0; ks2<2; ks2++){
      int s2 = st*16 + lr;
      va[st][ks2] = *(const short8*)(lo + s2*128 + ((ks2*64 + lk*16) ^ ((s2&7)<<4)));
    }
#pragma unroll
  for (int jt=0; jt<4; jt++)
#pragma unroll
    for (int ks2=0; ks2<2; ks2++){
      int j = jt*16 + lr;
      ab[jt][ks2] = *(const short8*)(hi + j*128 + ((ks2*64 + lk*16) ^ ((j&7)<<4)));
    }
  f32x4 at4[4][4];
#pragma unroll
  for (int st=0; st<4; st++)
#pragma unroll
    for (int jt=0; jt<4; jt++) at4[st][jt] = (f32x4){0.f,0.f,0.f,0.f};
#pragma unroll
  for (int st=0; st<4; st++)
#pragma unroll
    for (int jt=0; jt<4; jt++)
#pragma unroll
      for (int ks2=0; ks2<2; ks2++)
        at4[st][jt] = __builtin_amdgcn_mfma_f32_16x16x32_bf16(va[st][ks2], ab[jt][ks2], at4[st][jt], 0,0,0);
#pragma unroll
  for (int st=0; st<4; st++)
#pragma unroll
    for (int jt=0; jt<4; jt++){
      int d = jt*16 + lr;
      *(uint2*)(lo + d*128 + ((st*32 + lk*8) ^ ((d&7)<<4))) =
        (uint2){pk2(at4[st][jt][0], at4[st][jt][1]), pk2(at4[st][jt][2], at4[st][jt][3])};
    }

  // ---- GEMM4: out[c][d] = sum_s' Wo[c][s'] attn[s'][d] -> o_slab[c][d] (R6 verbatim, scalar) ----
  short8 tb[4][2];
#pragma unroll
  for (int dt=0; dt<4; dt++)
#pragma unroll
    for (int ks2=0; ks2<2; ks2++){
      int d = dt*16 + lr;
      tb[dt][ks2] = *(const short8*)(lo + d*128 + ((ks2*64 + lk*16) ^ ((d&7)<<4)));
    }
#pragma unroll
  for (int mt=0; mt<8; mt++){
    short8 wa[2];
#pragma unroll
    for (int ks2=0; ks2<2; ks2++)
      wa[ks2] = *(const short8*)(wo + (size_t)(mt*16 + lr)*64 + ks2*32 + lk*8);
    f32x4 oa[4];
#pragma unroll
    for (int dt=0; dt<4; dt++) oa[dt] = (f32x4){0.f,0.f,0.f,0.f};
#pragma unroll
    for (int dt=0; dt<4; dt++)
#pragma unroll
      for (int ks2=0; ks2<2; ks2++)
        oa[dt] = __builtin_amdgcn_mfma_f32_16x16x32_bf16(wa[ks2], tb[dt][ks2], oa[dt], 0,0,0);
#pragma unroll
    for (int dt=0; dt<4; dt++)
#pragma unroll
      for (int e=0; e<4; e++){
        int cc = mt*16 + lk*4 + e, d = dt*16 + lr;
        *(u16*)(slot + cc*128 + ((d*2) ^ ((cc&7)<<4))) = f2bf(oa[dt][e]);
      }
  }

  // ---- coalesced store: out_pre[n][c][d] (R6 verbatim) ----
  u16* og = out_pre + (size_t)n*8192;
#pragma unroll
  for (int r=0;r<16;r++){
    int j = r*64 + lane;          // j = cc*8 + o (o = d-octet)
    int cc = j>>3, o = j&7;
    uint4 v = *(const uint4*)(slot + cc*128 + ((o*16) ^ ((cc&7)<<4)));
    *(uint4*)(og + j*8) = v;
  }
}

// ---------------- K4: out = x + untranspose(out_pre) ----------------
__global__ __launch_bounds__(256) void k_merge(const float* x, const u16* out_pre, float* out){
  __shared__ u16 lm[32*512];   // 32 KB
  int t = threadIdx.x;
  int bid = blockIdx.x;
  int bh = bid>>2, cq = bid&3;
  int b = bh>>5, h = bh&31;
  int n0 = bh*32;
  int cbase = cq*32;
  int s = t>>3, q = t&7;
  for (int cc=0; cc<4; cc++){
    int cb = cbase + cc*8;
    {
      int n = s;
      int oq = q ^ ((n>>3)&3);
      bool swp = (n & 4) != 0;
#pragma unroll
      for (int i=0;i<8;i++){
        uint4 raw = *(const uint4*)(out_pre + (size_t)(n0+n)*8192 + (cb+i)*64 + q*8);
        if (swp){ u32 tx=raw.x, ty=raw.y; raw.x=raw.z; raw.y=raw.w; raw.z=tx; raw.w=ty; }
        *(uint4*)&lm[n*512 + i*64 + oq*8] = raw;
      }
    }
    __syncthreads();
    {
      int w4 = q*4;
#pragma unroll
      for (int g=0; g<16; g++){
        int row = g*32 + s;
        int ci = row>>6, d = row&63;
        size_t gi = ((size_t)((b*128 + cb + ci)*64 + d))*1024 + h*32 + w4;
        float4 xv = *(const float4*)(x + gi);
        float4 ov;
        ov.x = xv.x + bf2f(lm[(w4+0)*512 + (row ^ ((w4+0)&28))]);
        ov.y = xv.y + bf2f(lm[(w4+1)*512 + (row ^ ((w4+1)&28))]);
        ov.z = xv.z + bf2f(lm[(w4+2)*512 + (row ^ ((w4+2)&28))]);
        ov.w = xv.w + bf2f(lm[(w4+3)*512 + (row ^ ((w4+3)&28))]);
        *(float4*)(out + gi) = ov;
      }
    }
    __syncthreads();
  }
}

extern "C" void kernel_launch(void* const* d_in, const int* in_sizes, int n_in,
                              void* d_out, int out_size, void* d_ws, size_t ws_size,
                              hipStream_t stream){
  const float* x     = (const float*)d_in[0];
  const float* Wk    = (const float*)d_in[1];
  const float* Wq    = (const float*)d_in[2];
  const float* Wv    = (const float*)d_in[3];
  const float* Wo    = (const float*)d_in[4];
  const float* gamma = (const float*)d_in[5];
  const float* beta  = (const float*)d_in[6];
  float* out = (float*)d_out;
  char* ws = (char*)d_ws;

  float* part  = (float*)(ws + WS_PART);
  float* scale = (float*)(ws + WS_SCALE);
  float* shift = (float*)(ws + WS_SHIFT);
  u16* wkqv  = (u16*)(ws + WS_WKQV);
  u16* wo_bf = (u16*)(ws + WS_WO);
  u16* outp  = (u16*)(ws + WS_OUTP);
  u16* xn_t  = (u16*)d_out;   // scratch in d_out; dead before k_merge writes

  k_prep  <<<32,   256, 0, stream>>>(Wk, Wq, Wv, Wo, wkqv, wo_bf);
  k_stats1<<<1024, 256, 0, stream>>>(x, part);
  k_stats2<<<1,    128, 0, stream>>>(part, gamma, beta, scale, shift);
  k_norm_t<<<2048, 256, 0, stream>>>(x, scale, shift, xn_t);
  k_attn  <<<2048, 256, 0, stream>>>(xn_t, wkqv, wo_bf, outp);
  k_merge <<<1024, 256, 0, stream>>>(x, outp, out);
}